// Round 1
// baseline (579.932 us; speedup 1.0000x reference)
//
#include <hip/hip_runtime.h>
#include <hip/hip_bf16.h>
#include <cmath>

#define T_STEPS 16
#define BATCH   512
#define N_IN    3072
#define S1      256
#define S2      256
#define S3      128
#define NEXP    8
#define M_ROWS  (T_STEPS * BATCH)   // 8192
#define MT_ALL  (M_ROWS / 32)       // 256 m-tiles

typedef int v4i  __attribute__((ext_vector_type(4)));
typedef int v16i __attribute__((ext_vector_type(16)));
typedef unsigned long long u64;
typedef unsigned int uint32;

// ---------------------------------------------------------------------------
// pack binary fp32 x -> 1 bit/elem, TRANSPOSED: bitsT[kw][m'], m' = b*16+t.
// ---------------------------------------------------------------------------
__global__ __launch_bounds__(256) void pack_x_bits(
    const float* __restrict__ x, u64* __restrict__ bitsT)
{
    int gid = blockIdx.x * 256 + threadIdx.x;
    float v = x[gid];
    u64 m = __ballot(v >= 0.5f);
    if ((threadIdx.x & 63) == 0) {
        int tb = gid / N_IN;                 // t*512 + b
        int k  = gid - tb * N_IN;
        int t  = tb >> 9;
        int b  = tb & 511;
        bitsT[(size_t)(k >> 6) * M_ROWS + (b * 16 + t)] = m;
    }
}

// ---------------------------------------------------------------------------
// R10: expand bitsT -> i8 MFMA A-fragment tiles Af[kb][mt][lane][16],
// frag byte = bit(m = mt*32 + (lane&31), k = kb*32 + (lane>>5)*16 + byte).
// Kills the 128x-redundant in-loop unpack in stage 1 (each nblk re-unpacked
// the same A bits; VALUBusy 53% > MfmaUtil 42%).
// Reads 3 MB (x4 amplified), writes 24 MB -> ~6 us.
// ---------------------------------------------------------------------------
__global__ __launch_bounds__(256) void expand_a_frag(
    const u64* __restrict__ bitsT, char* __restrict__ Af)
{
    int t    = blockIdx.x * 256 + threadIdx.x;   // (kb*256 + mt)*64 + lane
    int lane = t & 63;
    int mt   = (t >> 6) & 255;
    int kb   = t >> 14;                          // 0..95
    int m    = mt * 32 + (lane & 31);
    int k0   = kb * 32 + (lane >> 5) * 16;
    u64 w = bitsT[(size_t)(k0 >> 6) * M_ROWS + m];
    uint32 w16 = (uint32)(w >> (k0 & 63)) & 0xFFFFu;   // k0&63 in {0,16,32,48}
    v4i d;
    #pragma unroll
    for (int c = 0; c < 4; ++c)
        d[c] = (int)((((w16 >> (4 * c)) & 0xFu) * 0x00204081u) & 0x01010101u);
    *(v4i*)(Af + (size_t)t * 16) = d;
}

// ---------------------------------------------------------------------------
// Weight digitize -> MFMA fragment tiles. B-row gr = o*32 + e*4 + limb.
// Bf[kb][nt=o][lane16][16], lane16 = (e*4+limb) + 32*qd, k = kb*32+qd*16+byte.
// ---------------------------------------------------------------------------
template<int S, int K>
__global__ __launch_bounds__(256) void digitize_w_frag(
    const float* __restrict__ W, char* __restrict__ Bf)
{
    constexpr int LOGS = (S == 256) ? 8 : 7;
    int t = blockIdx.x * 256 + threadIdx.x;   // chunks = 2*S*K
    int lane16 = t & 63;
    int o  = (t >> 6) & (S - 1);
    int kb = t >> (6 + LOGS);
    int r  = lane16 & 31;
    int qd = lane16 >> 5;
    int e    = r >> 2;
    int limb = r & 3;
    int k0 = kb * 32 + qd * 16;

    const float4* Wp = (const float4*)(W + ((size_t)e * S + o) * K + k0);
    char out[16];
    #pragma unroll
    for (int f4 = 0; f4 < 4; ++f4) {
        float4 w = Wp[f4];
        float ws[4] = {w.x, w.y, w.z, w.w};
        #pragma unroll
        for (int c = 0; c < 4; ++c) {
            long long q = llrint((double)ws[c] * 4294967296.0);
            int d = 0;
            #pragma unroll
            for (int l = 0; l < 4; ++l) {
                int dl = (int)((q + 128) & 255) - 128;
                q = (q - dl) >> 8;
                if (l == limb) d = dl;
            }
            out[f4 * 4 + c] = (char)d;
        }
    }
    *(v4i*)(Bf + (size_t)t * 16) = *(v4i*)out;
}

// ---------------------------------------------------------------------------
// Fused expert-GEMM + limb recombine + LIF + gated combine + mean.
// Block 256(m') x 64(B-rows): 4 waves stacked in m, ALL waves share identical
// B-fragment addresses (L1 hits for trailing waves). Wave tile 64x64.
// A: ABITS ? transposed bit rows (in-loop unpack) : fragment-tile i8
// (contiguous 1KB loads, same form as B; used by ALL stages when ws allows).
// Counts OUTPUT is also fragment-tile layout (k = this stage's o).
// 1-D grid, XCD swizzle: xcd = id&7 owns one n-slab -> B L2-resident.
// ---------------------------------------------------------------------------
template<int K, int S, int SHIFT, bool ABITS, bool WRITEC, int NBLK>
__global__ __launch_bounds__(256, 3) void fused_stage(
    const void* __restrict__ Ap, const char* __restrict__ Bf,
    const float* __restrict__ g, char* __restrict__ Cf,
    float* __restrict__ Mean)
{
    constexpr int KI = K / 64;
    constexpr int NT = S;                    // 32-row n-tiles in Bf
    constexpr int NS = NBLK / 8;
    __shared__ double hs[256][16];

    const int tid  = threadIdx.x;
    const int lane = tid & 63;
    const int w    = tid >> 6;
    const int col  = lane & 31;
    const int qd   = lane >> 5;
    const int wm   = w * 64;

    // XCD-swizzled block mapping: id = mblk*NBLK + inner*8 + xcd
    const int id   = blockIdx.x;
    const int nblk = (id & 7) * NS + ((id >> 3) % NS);
    const int mblk = id / NBLK;
    const int m0   = mblk * 256;

    const int nt0 = nblk * 2;
    const char* Bbase = Bf + ((size_t)nt0 * 64 + lane) * 16;

    v16i acc[2][2];
    #pragma unroll
    for (int i = 0; i < 2; ++i)
        #pragma unroll
        for (int j = 0; j < 2; ++j)
            #pragma unroll
            for (int r = 0; r < 16; ++r) acc[i][j][r] = 0;

    auto loadB = [&](int kb, int jj) -> v4i {
        return *(const v4i*)(Bbase + (size_t)kb * (NT * 1024) + jj * 1024);
    };

    v4i Bb[3][4];

    if constexpr (ABITS) {
        // transposed bits: AT[it][m'], contiguous in m'
        const u64* AT = (const u64*)Ap + (m0 + wm + col);
        const int sh16 = qd * 16;
        auto unpack16 = [&](uint32 dw) -> v4i {
            uint32 w16 = dw >> sh16;
            v4i d;
            #pragma unroll
            for (int c = 0; c < 4; ++c)
                d[c] = (int)((((w16 >> (4 * c)) & 0xFu) * 0x00204081u) & 0x01010101u);
            return d;
        };
        u64 a0b[3], a1b[3];
        #pragma unroll
        for (int s = 0; s < 2; ++s) {
            #pragma unroll
            for (int ks = 0; ks < 2; ++ks)
                #pragma unroll
                for (int jj = 0; jj < 2; ++jj)
                    Bb[s][ks * 2 + jj] = loadB(s * 2 + ks, jj);
            a0b[s] = AT[(size_t)s * M_ROWS];
            a1b[s] = AT[(size_t)s * M_ROWS + 32];
        }
        auto body = [&](int it, int cur, int pf) {
            const int itp = (it + 2 < KI) ? it + 2 : KI - 1;
            #pragma unroll
            for (int ks = 0; ks < 2; ++ks)
                #pragma unroll
                for (int jj = 0; jj < 2; ++jj)
                    Bb[pf][ks * 2 + jj] = loadB(itp * 2 + ks, jj);
            a0b[pf] = AT[(size_t)itp * M_ROWS];
            a1b[pf] = AT[(size_t)itp * M_ROWS + 32];
            #pragma unroll
            for (int ks = 0; ks < 2; ++ks) {
                uint32 dw0 = ks ? (uint32)(a0b[cur] >> 32) : (uint32)a0b[cur];
                uint32 dw1 = ks ? (uint32)(a1b[cur] >> 32) : (uint32)a1b[cur];
                v4i af0 = unpack16(dw0);
                v4i af1 = unpack16(dw1);
                acc[0][0] = __builtin_amdgcn_mfma_i32_32x32x32_i8(af0, Bb[cur][ks*2+0], acc[0][0], 0,0,0);
                acc[0][1] = __builtin_amdgcn_mfma_i32_32x32x32_i8(af0, Bb[cur][ks*2+1], acc[0][1], 0,0,0);
                acc[1][0] = __builtin_amdgcn_mfma_i32_32x32x32_i8(af1, Bb[cur][ks*2+0], acc[1][0], 0,0,0);
                acc[1][1] = __builtin_amdgcn_mfma_i32_32x32x32_i8(af1, Bb[cur][ks*2+1], acc[1][1], 0,0,0);
            }
        };
        static_assert(KI % 3 == 0, "bits path wants KI divisible by 3");
        for (int itb = 0; itb < KI; itb += 3) {
            body(itb + 0, 0, 2);
            body(itb + 1, 1, 0);
            body(itb + 2, 2, 1);
        }
    } else {
        // A in fragment-tile layout: Af[kb][mt][lane][16]
        const int mt0 = (m0 + wm) >> 5;
        const char* Abase = (const char*)Ap + ((size_t)mt0 * 64 + lane) * 16;
        auto loadA = [&](int kb, int ii) -> v4i {
            return *(const v4i*)(Abase + (size_t)kb * (MT_ALL * 1024) + ii * 1024);
        };
        v4i Ab[3][4];
        #pragma unroll
        for (int s = 0; s < 2; ++s) {
            #pragma unroll
            for (int ks = 0; ks < 2; ++ks) {
                Ab[s][ks * 2 + 0] = loadA(s * 2 + ks, 0);
                Ab[s][ks * 2 + 1] = loadA(s * 2 + ks, 1);
                #pragma unroll
                for (int jj = 0; jj < 2; ++jj)
                    Bb[s][ks * 2 + jj] = loadB(s * 2 + ks, jj);
            }
        }
        auto body = [&](int it, int cur, int pf) {
            const int itp = (it + 2 < KI) ? it + 2 : KI - 1;
            #pragma unroll
            for (int ks = 0; ks < 2; ++ks) {
                Ab[pf][ks * 2 + 0] = loadA(itp * 2 + ks, 0);
                Ab[pf][ks * 2 + 1] = loadA(itp * 2 + ks, 1);
                #pragma unroll
                for (int jj = 0; jj < 2; ++jj)
                    Bb[pf][ks * 2 + jj] = loadB(itp * 2 + ks, jj);
            }
            #pragma unroll
            for (int ks = 0; ks < 2; ++ks) {
                acc[0][0] = __builtin_amdgcn_mfma_i32_32x32x32_i8(Ab[cur][ks*2+0], Bb[cur][ks*2+0], acc[0][0], 0,0,0);
                acc[0][1] = __builtin_amdgcn_mfma_i32_32x32x32_i8(Ab[cur][ks*2+0], Bb[cur][ks*2+1], acc[0][1], 0,0,0);
                acc[1][0] = __builtin_amdgcn_mfma_i32_32x32x32_i8(Ab[cur][ks*2+1], Bb[cur][ks*2+0], acc[1][0], 0,0,0);
                acc[1][1] = __builtin_amdgcn_mfma_i32_32x32x32_i8(Ab[cur][ks*2+1], Bb[cur][ks*2+1], acc[1][1], 0,0,0);
            }
        };
        static_assert(KI == 4 || KI % 3 == 0, "frag path KI form");
        if constexpr (KI == 4) {
            body(0, 0, 2);
            body(1, 1, 0);
            body(2, 2, 1);
            body(3, 0, 2);
        } else {
            // rolling triple-buffer, distance-2 prefetch (covers ~200cy L2)
            for (int itb = 0; itb < KI; itb += 3) {
                body(itb + 0, 0, 2);
                body(itb + 1, 1, 0);
                body(itb + 2, 2, 1);
            }
        }
    }

    // ---- limb recombine (exact, in double) -> LDS h tile ----
    const double sbase = 1.0 / (double)(1ll << SHIFT);
    const int limb = col & 3;
    const double lscale = (double)(1 << (8 * limb)) * sbase;
    #pragma unroll
    for (int j = 0; j < 2; ++j) {
        const int oe = j * 8 + (col >> 2);            // o_loc*8 + e
        #pragma unroll
        for (int i = 0; i < 2; ++i) {
            #pragma unroll
            for (int reg = 0; reg < 16; ++reg) {
                double d = (double)acc[i][j][reg] * lscale;
                d += __shfl_xor(d, 1);
                d += __shfl_xor(d, 2);
                if ((col & 3) == 0) {
                    int m = wm + i * 32 + (reg & 3) + 8 * (reg >> 2) + 4 * qd;
                    hs[m][oe] = d;
                }
            }
        }
    }
    __syncthreads();

    // ---- LIF scan: thread = (b_loc = tid>>4, o_loc = (tid>>3)&1, e = tid&7)
    const int b_loc  = tid >> 4;
    const int o_loc  = (tid >> 3) & 1;
    const int e      = tid & 7;
    const int oe     = o_loc * 8 + e;
    const float ge   = g[e];
    const int bg = mblk * 16 + b_loc;
    const int og = nblk * 2 + o_loc;

    // fragment-tile write coords for counts (k = og of this stage)
    const int kb_a   = og >> 5;
    const int qd_a   = (og >> 4) & 1;
    const int byte_a = og & 15;

    double v = 0.0;
    float gacc = 0.0f;
    #pragma unroll
    for (int t = 0; t < T_STEPS; ++t) {
        double h  = hs[b_loc * 16 + t][oe];
        double vv = v * 0.95 + h;
        int spk = (vv >= 1.0) ? 1 : 0;
        v = vv - (double)spk;
        float gs = ge * (float)spk;
        gs += __shfl_xor(gs, 1);
        gs += __shfl_xor(gs, 2);
        gs += __shfl_xor(gs, 4);
        gacc += gs;
        if (WRITEC) {
            int cnt = spk;
            cnt += __shfl_xor(cnt, 1);
            cnt += __shfl_xor(cnt, 2);
            cnt += __shfl_xor(cnt, 4);
            if (e == 0) {
                int mp = bg * 16 + t;
                int lane_a = (mp & 31) + 32 * qd_a;
                Cf[(((size_t)kb_a * MT_ALL + (mp >> 5)) * 64 + lane_a) * 16 + byte_a]
                    = (char)cnt;
            }
        }
    }
    if (e == 0) Mean[(size_t)bg * S + og] = gacc * 0.0625f;
}

// ---------------------------------------------------------------------------
// ws layout (bytes), frag-A path (needs 58 MB):
//   AbitsT @ 0          : 3 MB   (48 x 8192 u64, transposed)
//   A1f    @ 3145728    : 24 MB  (i8 A fragments for stage 1)
//   B1f    @ 28311552   : 24 MB
//   B2f    @ 53477376   :  2 MB
//   B3f    @ 55574528   :  1 MB
//   c1f    @ 56623104   :  2 MB
//   c2f    @ 58720256   :  2 MB   -> total 60817408
// Fallback (ws < 58 MB): original 34 MB layout with in-loop bit unpack.
// ---------------------------------------------------------------------------
extern "C" void kernel_launch(void* const* d_in, const int* in_sizes, int n_in,
                              void* d_out, int out_size, void* d_ws, size_t ws_size,
                              hipStream_t stream) {
    const float* x  = (const float*)d_in[0];
    const float* W1 = (const float*)d_in[1];
    const float* W2 = (const float*)d_in[2];
    const float* W3 = (const float*)d_in[3];
    const float* g1 = (const float*)d_in[4];
    const float* g2 = (const float*)d_in[5];
    const float* g3 = (const float*)d_in[6];
    float* out = (float*)d_out;

    char* ws = (char*)d_ws;
    dim3 blk(256);

    if (ws_size >= 60817408ull) {
        u64*  AbitsT = (u64*)ws;
        char* A1f    = ws + 3145728ull;
        char* B1f    = ws + 28311552ull;
        char* B2f    = ws + 53477376ull;
        char* B3f    = ws + 55574528ull;
        char* c1f    = ws + 56623104ull;
        char* c2f    = ws + 58720256ull;

        // --- precompute ---
        pack_x_bits<<<(M_ROWS * N_IN) / 256, blk, 0, stream>>>(x, AbitsT);
        expand_a_frag<<<(96 * 256 * 64) / 256, blk, 0, stream>>>(AbitsT, A1f);
        digitize_w_frag<S1, N_IN><<<(2 * S1 * N_IN) / 256, blk, 0, stream>>>(W1, B1f);
        digitize_w_frag<S2, S1><<<(2 * S2 * S1) / 256, blk, 0, stream>>>(W2, B2f);
        digitize_w_frag<S3, S2><<<(2 * S3 * S2) / 256, blk, 0, stream>>>(W3, B3f);

        // --- three fused GEMM+LIF stages, all on the fragment-A path ---
        fused_stage<N_IN, S1, 32, false, true,  128><<<32 * 128, blk, 0, stream>>>(
            A1f, B1f, g1, c1f, out);
        fused_stage<S1,   S2, 35, false, true,  128><<<32 * 128, blk, 0, stream>>>(
            c1f, B2f, g2, c2f, out + BATCH * S1);
        fused_stage<S2,   S3, 35, false, false, 64><<<32 * 64, blk, 0, stream>>>(
            c2f, B3f, g3, nullptr, out + BATCH * (S1 + S2));
    } else {
        u64*  AbitsT = (u64*)ws;
        char* B1f    = ws + 3145728ull;
        char* B2f    = ws + 28311552ull;
        char* B3f    = ws + 30408704ull;
        char* c1f    = ws + 31457280ull;
        char* c2f    = ws + 33554432ull;

        pack_x_bits<<<(M_ROWS * N_IN) / 256, blk, 0, stream>>>(x, AbitsT);
        digitize_w_frag<S1, N_IN><<<(2 * S1 * N_IN) / 256, blk, 0, stream>>>(W1, B1f);
        digitize_w_frag<S2, S1><<<(2 * S2 * S1) / 256, blk, 0, stream>>>(W2, B2f);
        digitize_w_frag<S3, S2><<<(2 * S3 * S2) / 256, blk, 0, stream>>>(W3, B3f);

        fused_stage<N_IN, S1, 32, true,  true,  128><<<32 * 128, blk, 0, stream>>>(
            AbitsT, B1f, g1, c1f, out);
        fused_stage<S1,   S2, 35, false, true,  128><<<32 * 128, blk, 0, stream>>>(
            c1f, B2f, g2, c2f, out + BATCH * S1);
        fused_stage<S2,   S3, 35, false, false, 64><<<32 * 64, blk, 0, stream>>>(
            c2f, B3f, g3, nullptr, out + BATCH * (S1 + S2));
    }
}